// Round 9
// baseline (133.936 us; speedup 1.0000x reference)
//
#include <hip/hip_runtime.h>
#include <math.h>

#define N_NODES 2048
#define T_WIN 5
#define D_EMB 64
#define TOPK 21
#define B_BATCH 32
#define BN_TOTAL (B_BATCH * N_NODES)   // 65536
#define EPS_BN 1e-5f
#define NEG_SLOPE 0.2f
#define STATS_STRIDE 16

typedef unsigned long long u64;

// ---------------- wave-level helpers (wave = 64 on gfx950) ----------------
__device__ __forceinline__ float wave_sum(float v) {
#pragma unroll
    for (int off = 32; off > 0; off >>= 1) v += __shfl_xor(v, off, 64);
    return v;
}

__device__ __forceinline__ u64 max64(u64 a, u64 b) { return a > b ? a : b; }
__device__ __forceinline__ u64 min64(u64 a, u64 b) { return a < b ? a : b; }

__device__ __forceinline__ u64 bitonic_sort64_desc(u64 key, int lane) {
#pragma unroll
    for (int k = 2; k <= 64; k <<= 1) {
#pragma unroll
        for (int j = k >> 1; j >= 1; j >>= 1) {
            u64 pk = __shfl_xor(key, j, 64);
            bool dirDesc = ((lane & k) == 0);
            bool keepMax = (((lane & j) == 0) == dirDesc);
            key = keepMax ? max64(key, pk) : min64(key, pk);
        }
    }
    return key;
}

__device__ __forceinline__ u64 bitonic_merge_top64(u64 a, u64 b, int lane) {
    u64 br = __shfl(b, 63 - lane, 64);
    u64 c = max64(a, br);
#pragma unroll
    for (int j = 32; j >= 1; j >>= 1) {
        u64 pk = __shfl_xor(c, j, 64);
        bool keepMax = ((lane & j) == 0);
        c = keepMax ? max64(c, pk) : min64(c, pk);
    }
    return c;
}

// ---------------- K1: k_preg — fused {raw Gram tiles} + {edge precompute} ---
// [R7: gram writes RAW dots, /(ni*nj) in k_select — bit-identical keys.]
// [R9: tile + transpose staged in dead As/Bs LDS after the acc loop, then
//  BOTH images written with fully-coalesced 1KB-per-instruction float4
//  stores (was: scattered 16B primary + 16 scalar mirror stores/thread).
//  Same values to same addresses -> bit-identical.]
// [R8 post-mortem: cooperative grid.sync handoff of plain stores across XCDs
//  FAILED (absmax 10.5) — kernel boundaries are the only proven device fence.]
__global__ __launch_bounds__(256) void k_preg(
    const float* __restrict__ x, const float* __restrict__ W,
    const float* __restrict__ Wb, const float* __restrict__ a_src,
    const float* __restrict__ a_dst, const float* __restrict__ emb,
    float* __restrict__ xs2T, float* __restrict__ xd2T,
    float* __restrict__ es_embP, float* __restrict__ ed_embP,
    float* __restrict__ norms, float* __restrict__ dotM,
    float* __restrict__ stats, float* __restrict__ stats2) {
    __shared__ __align__(16) float As[64][68];   // [d][i] (gram path only)
    __shared__ __align__(16) float Bs[64][68];   // [d][j]
    int t = threadIdx.x;

    if (blockIdx.x >= 528) {
        int eb = blockIdx.x - 528;
        if (eb < 512) {
            // ---- node path: norms + es_emb/ed_emb (wave per node) ----
            if (eb < 2) {
                float* p = eb ? stats2 : stats;
                ((float4*)p)[t] = make_float4(0.f, 0.f, 0.f, 0.f);
            }
            int wid = t >> 6, lane = t & 63;
            int node = eb * 4 + wid;
            float e = emb[node * D_EMB + lane];
            float s2 = wave_sum(e * e);
            float esE = wave_sum(e * a_src[D_EMB + lane]);
            float edE = wave_sum(e * a_dst[D_EMB + lane]);
            if (lane == 0) {
                norms[node] = sqrtf(s2);
                es_embP[node] = esE;
                ed_embP[node] = edE;
            }
        } else {
            // ---- x path: xs/xd = bs + Sum_t x*w ----
            __shared__ float cws[5], cwd[5], cbs[2];
            if (t < 12) {
                int which = (t < 5 || t == 10) ? 0 : 1;
                const float* av = which ? a_dst : a_src;
                const float* sp;
                int stride;
                if (t < 10) { int tt = (t < 5) ? t : t - 5; sp = W + tt; stride = T_WIN; }
                else        { sp = Wb; stride = 1; }
                float acc = 0.f;
                for (int d = 0; d < D_EMB; d++) acc += sp[d * stride] * av[d];
                if (t < 5)       cws[t] = acc;
                else if (t < 10) cwd[t - 5] = acc;
                else             cbs[t - 10] = acc;
            }
            __syncthreads();
            float ws0 = cws[0], ws1 = cws[1], ws2 = cws[2], ws3 = cws[3], ws4 = cws[4];
            float wd0 = cwd[0], wd1 = cwd[1], wd2 = cwd[2], wd3 = cwd[3], wd4 = cwd[4];
            float bss = cbs[0], bsd = cbs[1];
            int base = (eb - 512) * 1024;
#pragma unroll
            for (int r = 0; r < 4; r++) {
                int item = base + 256 * r + t;
                const float* xp = x + (size_t)item * T_WIN;
                float x0 = xp[0], x1 = xp[1], x2 = xp[2], x3 = xp[3], x4 = xp[4];
                xs2T[item] = bss + x0 * ws0 + x1 * ws1 + x2 * ws2 + x3 * ws3 + x4 * ws4;
                xd2T[item] = bsd + x0 * wd0 + x1 * wd1 + x2 * wd2 + x3 * wd3 + x4 * wd4;
            }
        }
        return;
    }

    // ---- gram path: raw Gram tile, symmetric write (dot exactly symmetric)
    int g = blockIdx.x;                          // 0..527
    int a = (int)((sqrtf(8.f * g + 1.f) - 1.f) * 0.5f);
    while ((a + 1) * (a + 2) / 2 <= g) a++;
    while (a * (a + 1) / 2 > g) a--;
    int bq = g - a * (a + 1) / 2;                // 0..a
    int i0 = a * 64, j0 = bq * 64;

    {
        int r = t >> 2, c0 = t & 3;
        const float4* srcA = (const float4*)(emb + (size_t)(i0 + r) * D_EMB);
        const float4* srcB = (const float4*)(emb + (size_t)(j0 + r) * D_EMB);
#pragma unroll
        for (int k = 0; k < 4; k++) {
            int f4 = c0 + 4 * k;
            float4 v = srcA[f4];
            int d = 4 * f4;
            As[d][r] = v.x; As[d + 1][r] = v.y; As[d + 2][r] = v.z; As[d + 3][r] = v.w;
            float4 w = srcB[f4];
            Bs[d][r] = w.x; Bs[d + 1][r] = w.y; Bs[d + 2][r] = w.z; Bs[d + 3][r] = w.w;
        }
    }
    __syncthreads();

    int ti = t & 15, tj = t >> 4;
    float acc[4][4] = {};
#pragma unroll
    for (int d = 0; d < 64; d++) {
        float4 av = *(const float4*)&As[d][4 * ti];
        float4 bv = *(const float4*)&Bs[d][4 * tj];
        acc[0][0] += av.x * bv.x; acc[0][1] += av.x * bv.y; acc[0][2] += av.x * bv.z; acc[0][3] += av.x * bv.w;
        acc[1][0] += av.y * bv.x; acc[1][1] += av.y * bv.y; acc[1][2] += av.y * bv.z; acc[1][3] += av.y * bv.w;
        acc[2][0] += av.z * bv.x; acc[2][1] += av.z * bv.y; acc[2][2] += av.z * bv.z; acc[2][3] += av.z * bv.w;
        acc[3][0] += av.w * bv.x; acc[3][1] += av.w * bv.y; acc[3][2] += av.w * bv.z; acc[3][3] += av.w * bv.w;
    }

    // stage tile + transpose in the now-dead As/Bs, then coalesced writes
    __syncthreads();
    float (*Ts)[68] = As;          // Ts[row][col] = T
    float (*Tt)[68] = Bs;          // Tt[col][row] = T^T
#pragma unroll
    for (int r = 0; r < 4; r++) {
        *(float4*)&Ts[4 * ti + r][4 * tj] =
            make_float4(acc[r][0], acc[r][1], acc[r][2], acc[r][3]);
        Tt[4 * tj + 0][4 * ti + r] = acc[r][0];
        Tt[4 * tj + 1][4 * ti + r] = acc[r][1];
        Tt[4 * tj + 2][4 * ti + r] = acc[r][2];
        Tt[4 * tj + 3][4 * ti + r] = acc[r][3];
    }
    __syncthreads();
    {
        int wd = t >> 6, ln = t & 63;
        int sub = ln >> 4, cc = (ln & 15) * 4;
#pragma unroll
        for (int k4 = 0; k4 < 4; k4++) {
            int rr = wd * 16 + k4 * 4 + sub;     // wave covers 4 consecutive rows/instr
            *(float4*)(dotM + (size_t)(i0 + rr) * N_NODES + j0 + cc) =
                *(const float4*)&Ts[rr][cc];
            *(float4*)(dotM + (size_t)(j0 + rr) * N_NODES + i0 + cc) =
                *(const float4*)&Tt[rr][cc];
        }
    }
}

// ---------------- K2: top-21 selection — 4 waves/row, on-the-fly norm -------
// NEW (r9): one row per block; each wave scans a 512-entry quarter (8 chunks,
// own top-64 state + flushes); wave 0 chains 3 bitonic merges over the
// published quarter-top-64s. Merged top-64 of four quarter-top-64s contains
// the exact top-21 (same keys, same ~j tie-break) -> selection identical.
// Grid 2048 blocks -> 8 waves/SIMD; serial ballot/shfl chain halves vs R5.
__global__ __launch_bounds__(256) void k_select(
    const float* __restrict__ dotM, const float* __restrict__ norms,
    int* __restrict__ idxT) {
    __shared__ u64 candbuf[4][128];
    __shared__ u64 mbuf[3][64];
    int tid = threadIdx.x;
    int wid = tid >> 6, lane = tid & 63;
    int i = blockIdx.x;
    int jbase = wid * (N_NODES / 4);
    const float* row = dotM + (size_t)i * N_NODES + jbase;
    u64* buf = candbuf[wid];
    float ni = norms[i];

    u64 a = 0;
    u64 t = 0;
    int cnt = 0;
    float vcur = row[lane];
    float ncur = norms[jbase + lane];

#pragma unroll 1
    for (int c = 0; c < N_NODES / 256; c++) {   // 8 chunks of 64
        int j = c * 64 + lane;
        float dv = vcur, nv = ncur;
        if (c < N_NODES / 256 - 1) {
            vcur = row[j + 64];
            ncur = norms[jbase + j + 64];
        }
        float v = dv / (ni * nv);
        unsigned u = __float_as_uint(v);
        u = (u & 0x80000000u) ? ~u : (u | 0x80000000u);
        u64 key = ((u64)u << 32) | (unsigned)(~(j + jbase));
        unsigned long long ball = __ballot(key > t);
        if (ball) {
            int ofs = __popcll(ball & ((1ull << lane) - 1ull));
            if (key > t) buf[cnt + ofs] = key;
            cnt += (int)__popcll(ball);
            if (cnt >= 64) {
                u64 nk = buf[lane];
                nk = bitonic_sort64_desc(nk, lane);
                a = bitonic_merge_top64(a, nk, lane);
                t = __shfl(a, 20, 64);
                int rem = cnt - 64;
                u64 mv = (lane < rem) ? buf[64 + lane] : 0;
                if (lane < rem) buf[lane] = mv;
                cnt = rem;
            }
        }
    }
    while (cnt > 0) {
        int take = cnt < 64 ? cnt : 64;
        u64 nk = (lane < take) ? buf[lane] : 0;
        nk = bitonic_sort64_desc(nk, lane);
        a = bitonic_merge_top64(a, nk, lane);
        t = __shfl(a, 20, 64);
        int rem = cnt - take;
        u64 mv = (lane < rem) ? buf[take + lane] : 0;
        if (lane < rem) buf[lane] = mv;
        cnt = rem;
    }

    // 4-way merge: waves 1..3 publish; wave 0 chains merges and writes
    if (wid) mbuf[wid - 1][lane] = a;
    __syncthreads();
    if (wid == 0) {
        a = bitonic_merge_top64(a, mbuf[0][lane], lane);
        a = bitonic_merge_top64(a, mbuf[1][lane], lane);
        a = bitonic_merge_top64(a, mbuf[2][lane], lane);
        if (lane < TOPK) idxT[lane * N_NODES + i] = (int)(~(unsigned)a);
    }
}

// ---------------- K3: k_alpha — softmax from decomposed es/ed ---------------
__global__ __launch_bounds__(256) void k_alpha(
    const int* __restrict__ idxT, const float* __restrict__ xs2T,
    const float* __restrict__ xd2T, const float* __restrict__ es_embP,
    const float* __restrict__ ed_embP, float* __restrict__ alphaT) {
    __shared__ float sed[N_NODES];   // 8 KB
    int g = blockIdx.x;
    int b = g & 31;
    int i0 = (g >> 5) * 256;
    int t = threadIdx.x;

    {
        const float4* sxd = (const float4*)(xd2T + (size_t)b * N_NODES);
        const float4* sde = (const float4*)(ed_embP);
        float4* dst = (float4*)sed;
#pragma unroll
        for (int q = 0; q < 2; q++) {
            int idx = t + 256 * q;
            float4 u = sxd[idx];
            float4 v = sde[idx];
            dst[idx] = make_float4(u.x + v.x, u.y + v.y, u.z + v.z, u.w + v.w);
        }
    }
    __syncthreads();

    int i = i0 + t;
    float es = xs2T[(size_t)b * N_NODES + i] + es_embP[i];
    float ev[TOPK];
    float m = -3e38f;
#pragma unroll
    for (int k = 0; k < TOPK; k++) {
        int jk = idxT[k * N_NODES + i];
        float e = es + sed[jk];
        e = e > 0.f ? e : NEG_SLOPE * e;
        ev[k] = e;
        m = fmaxf(m, e);
    }
    float s = 0.f;
#pragma unroll
    for (int k = 0; k < TOPK; k++) {
        ev[k] = __expf(ev[k] - m);
        s += ev[k];
    }
    float inv = 1.0f / s;
#pragma unroll
    for (int k = 0; k < TOPK; k++)
        alphaT[((size_t)b * TOPK + k) * N_NODES + i] = ev[k] * inv;
}

// ---------------- K4: message passing — b128 h-tile, 4 blocks/CU ------------
// [R7: hts[2048][4] 32 KB -> one ds_read_b128/neighbor; 4 blocks/CU.]
__global__ __launch_bounds__(256, 4) void k_msg(
    const float* __restrict__ x, const float* __restrict__ W,
    const float* __restrict__ Wb, const int* __restrict__ idxT,
    const float* __restrict__ alphaT, const float* __restrict__ emb,
    float* __restrict__ obufT, float* __restrict__ stats,
    float* __restrict__ stats2) {
    __shared__ __align__(16) float hts[N_NODES][4];   // 32 KB, b128 rows
    __shared__ float sred[2][4][4];

    int g = blockIdx.x;                        // 512 = 32 b x 16 c
    int b = (g & 7) + 8 * ((g >> 3) & 3);      // XCD-local batches
    int c = g >> 5;
    int d0 = c * 4;
    int t = threadIdx.x;
    int wid = t >> 6, lane = t & 63;

    // ---- build h-tile from x ----
    float wc[4][T_WIN], wb4[4];
#pragma unroll
    for (int q = 0; q < 4; q++) {
        wb4[q] = Wb[d0 + q];
#pragma unroll
        for (int tt = 0; tt < T_WIN; tt++) wc[q][tt] = W[(d0 + q) * T_WIN + tt];
    }
    const float* xb = x + (size_t)b * N_NODES * T_WIN;
#pragma unroll
    for (int r = 0; r < 8; r++) {
        int row = t + 256 * r;
        const float* xr = xb + row * T_WIN;
        float x0 = xr[0], x1 = xr[1], x2 = xr[2], x3 = xr[3], x4 = xr[4];
        float h0 = wb4[0] + x0 * wc[0][0] + x1 * wc[0][1] + x2 * wc[0][2] + x3 * wc[0][3] + x4 * wc[0][4];
        float h1 = wb4[1] + x0 * wc[1][0] + x1 * wc[1][1] + x2 * wc[1][2] + x3 * wc[1][3] + x4 * wc[1][4];
        float h2 = wb4[2] + x0 * wc[2][0] + x1 * wc[2][1] + x2 * wc[2][2] + x3 * wc[2][3] + x4 * wc[2][4];
        float h3 = wb4[3] + x0 * wc[3][0] + x1 * wc[3][1] + x2 * wc[3][2] + x3 * wc[3][3] + x4 * wc[3][4];
        *(float4*)&hts[row][0] = make_float4(h0, h1, h2, h3);
    }
    __syncthreads();

    // ---- gather: 2048 items, 8 per thread ----
    float sacc[4] = {0.f, 0.f, 0.f, 0.f};
    float sacc2[4] = {0.f, 0.f, 0.f, 0.f};
    const float* aT = alphaT + (size_t)b * TOPK * N_NODES;
#pragma unroll 1
    for (int r = 0; r < 8; r++) {
        int i = 256 * r + t;
        float4 z = make_float4(0.f, 0.f, 0.f, 0.f);
#pragma unroll
        for (int k = 0; k < TOPK; k++) {
            int jk = idxT[k * N_NODES + i];          // coalesced, L2-resident
            float a = aT[(size_t)k * N_NODES + i];   // coalesced
            float4 h4 = *(const float4*)&hts[jk][0]; // one ds_read_b128
            z.x = fmaf(a, h4.x, z.x);
            z.y = fmaf(a, h4.y, z.y);
            z.z = fmaf(a, h4.z, z.z);
            z.w = fmaf(a, h4.w, z.w);
        }
        float4 e4 = *(const float4*)(emb + (size_t)i * D_EMB + d0);
        float4 o;
        o.x = fmaxf(z.x, 0.f) * e4.x;
        o.y = fmaxf(z.y, 0.f) * e4.y;
        o.z = fmaxf(z.z, 0.f) * e4.z;
        o.w = fmaxf(z.w, 0.f) * e4.w;
        ((float4*)obufT)[((size_t)c * B_BATCH + b) * N_NODES + i] = o;
        sacc[0] += o.x; sacc[1] += o.y; sacc[2] += o.z; sacc[3] += o.w;
        sacc2[0] += o.x * o.x; sacc2[1] += o.y * o.y;
        sacc2[2] += o.z * o.z; sacc2[3] += o.w * o.w;
    }

    // ---- stats partials ----
#pragma unroll
    for (int q = 0; q < 4; q++) {
        sacc[q] = wave_sum(sacc[q]);
        sacc2[q] = wave_sum(sacc2[q]);
    }
    if (lane == 0) {
#pragma unroll
        for (int q = 0; q < 4; q++) {
            sred[0][wid][q] = sacc[q];
            sred[1][wid][q] = sacc2[q];
        }
    }
    __syncthreads();
    if (t < 8) {
        int q = t & 3, which = t >> 2;
        float v = sred[which][0][q] + sred[which][1][q] + sred[which][2][q] + sred[which][3][q];
        float* dst = which ? stats2 : stats;
        atomicAdd(&dst[(d0 + q) * STATS_STRIDE], v);
    }
}

// ---------------- K5: BN apply + relu + fc — coalesced c-panel sweep --------
__global__ __launch_bounds__(256) void k_out(
    const float* __restrict__ obufT, const float* __restrict__ stats,
    const float* __restrict__ stats2, const float* __restrict__ gamma,
    const float* __restrict__ beta, const float* __restrict__ fc_w,
    const float* __restrict__ fc_b, float* __restrict__ out) {
    __shared__ float smean[64], sinv[64], sg[64], sb[64], sf[64];
    int t = threadIdx.x;
    int g = blockIdx.x;                 // 256 = 32 b x 8 n-chunks
    int b = g & 31, nc = g >> 5;
    int n = nc * 256 + t;
    const float invM = 1.0f / (float)BN_TOTAL;

    if (t < 64) {
        float mn = stats[t * STATS_STRIDE] * invM;
        float var = stats2[t * STATS_STRIDE] * invM - mn * mn;
        smean[t] = mn;
        sinv[t] = rsqrtf(var + EPS_BN);
        sg[t] = gamma[t]; sb[t] = beta[t]; sf[t] = fc_w[t];
    }
    __syncthreads();

    float fb = fc_b[0];
    float p = 0.f;
#pragma unroll
    for (int c = 0; c < 16; c++) {
        float4 o = ((const float4*)obufT)[((size_t)c * B_BATCH + b) * N_NODES + n];
        int d = 4 * c;
        float v;
        v = fmaxf((o.x - smean[d + 0]) * sinv[d + 0] * sg[d + 0] + sb[d + 0], 0.f); p = fmaf(v, sf[d + 0], p);
        v = fmaxf((o.y - smean[d + 1]) * sinv[d + 1] * sg[d + 1] + sb[d + 1], 0.f); p = fmaf(v, sf[d + 1], p);
        v = fmaxf((o.z - smean[d + 2]) * sinv[d + 2] * sg[d + 2] + sb[d + 2], 0.f); p = fmaf(v, sf[d + 2], p);
        v = fmaxf((o.w - smean[d + 3]) * sinv[d + 3] * sg[d + 3] + sb[d + 3], 0.f); p = fmaf(v, sf[d + 3], p);
    }
    out[b * N_NODES + n] = p + fb;
}

// ---------------- launch ----------------------------------------------------
extern "C" void kernel_launch(void* const* d_in, const int* in_sizes, int n_in,
                              void* d_out, int out_size, void* d_ws, size_t ws_size,
                              hipStream_t stream) {
    const float* x     = (const float*)d_in[0];
    const float* emb   = (const float*)d_in[1];
    const float* W     = (const float*)d_in[2];
    const float* Wb    = (const float*)d_in[3];
    const float* a_src = (const float*)d_in[4];
    const float* a_dst = (const float*)d_in[5];
    const float* gamma = (const float*)d_in[6];
    const float* beta  = (const float*)d_in[7];
    const float* fc_w  = (const float*)d_in[8];
    const float* fc_b  = (const float*)d_in[9];
    float* out = (float*)d_out;

    char* ws = (char*)d_ws;
    float* stats   = (float*)(ws + 0);            // 4 KB
    float* stats2  = (float*)(ws + 4096);         // 4 KB
    int*   idxT    = (int*)  (ws + 8192);         // 172032 B
    float* norms   = (float*)(ws + 180224);       // 8 KB
    float* es_embP = (float*)(ws + 188416);       // 8 KB
    float* ed_embP = (float*)(ws + 196608);       // 8 KB
    float* xs2T    = (float*)(ws + 204800);       // 256 KB [b][n]
    float* xd2T    = (float*)(ws + 466944);       // 256 KB [b][n]
    float* alphaT  = (float*)(ws + 729088);       // 5505024 B [b][k][i]
    float* dotM    = (float*)(ws + 6234112);      // 16 MB — aliased with obufT
    float* obufT   = dotM;                        // (dotM dead after k_select)
    // total: 23,011,328 bytes

    k_preg<<<1104, 256, 0, stream>>>(x, W, Wb, a_src, a_dst, emb,
                                     xs2T, xd2T, es_embP, ed_embP, norms,
                                     dotM, stats, stats2);
    k_select<<<N_NODES, 256, 0, stream>>>(dotM, norms, idxT);
    k_alpha<<<256, 256, 0, stream>>>(idxT, xs2T, xd2T, es_embP, ed_embP, alphaT);
    k_msg<<<512, 256, 0, stream>>>(x, W, Wb, idxT, alphaT, emb, obufT, stats, stats2);
    k_out<<<256, 256, 0, stream>>>(obufT, stats, stats2, gamma, beta, fc_w, fc_b, out);
}

// Round 10
// 128.620 us; speedup vs baseline: 1.0413x; 1.0413x over previous
//
#include <hip/hip_runtime.h>
#include <math.h>

#define N_NODES 2048
#define T_WIN 5
#define D_EMB 64
#define TOPK 21
#define B_BATCH 32
#define BN_TOTAL (B_BATCH * N_NODES)   // 65536
#define EPS_BN 1e-5f
#define NEG_SLOPE 0.2f
#define STATS_STRIDE 16

typedef unsigned long long u64;
typedef unsigned short u16;

// ---------------- wave-level helpers (wave = 64 on gfx950) ----------------
__device__ __forceinline__ float wave_sum(float v) {
#pragma unroll
    for (int off = 32; off > 0; off >>= 1) v += __shfl_xor(v, off, 64);
    return v;
}

__device__ __forceinline__ u64 max64(u64 a, u64 b) { return a > b ? a : b; }
__device__ __forceinline__ u64 min64(u64 a, u64 b) { return a < b ? a : b; }

__device__ __forceinline__ u64 bitonic_sort64_desc(u64 key, int lane) {
#pragma unroll
    for (int k = 2; k <= 64; k <<= 1) {
#pragma unroll
        for (int j = k >> 1; j >= 1; j >>= 1) {
            u64 pk = __shfl_xor(key, j, 64);
            bool dirDesc = ((lane & k) == 0);
            bool keepMax = (((lane & j) == 0) == dirDesc);
            key = keepMax ? max64(key, pk) : min64(key, pk);
        }
    }
    return key;
}

__device__ __forceinline__ u64 bitonic_merge_top64(u64 a, u64 b, int lane) {
    u64 br = __shfl(b, 63 - lane, 64);
    u64 c = max64(a, br);
#pragma unroll
    for (int j = 32; j >= 1; j >>= 1) {
        u64 pk = __shfl_xor(c, j, 64);
        bool keepMax = ((lane & j) == 0);
        c = keepMax ? max64(c, pk) : min64(c, pk);
    }
    return c;
}

// bf16 round-to-nearest-even pack/unpack (obufT only; 57x threshold headroom)
__device__ __forceinline__ u16 f2bf(float f) {
    unsigned u = __float_as_uint(f);
    return (u16)((u + 0x7FFFu + ((u >> 16) & 1u)) >> 16);
}
__device__ __forceinline__ float bf2f(u16 h) {
    return __uint_as_float((unsigned)h << 16);
}

// ---------------- K1: k_preg — fused {raw Gram tiles} + {edge precompute} ---
// [R7: gram writes RAW dots, /(ni*nj) in k_select — bit-identical keys.]
// [R9 post-mortem: LDS-transpose epilogue had 8-way-conflict scalar LDS
//  stores — reverted to direct scattered mirror writes (R7 form).]
// [R8 post-mortem: grid.sync handoff of plain stores across XCDs FAILED —
//  kernel boundaries are the only proven device fence.]
__global__ __launch_bounds__(256) void k_preg(
    const float* __restrict__ x, const float* __restrict__ W,
    const float* __restrict__ Wb, const float* __restrict__ a_src,
    const float* __restrict__ a_dst, const float* __restrict__ emb,
    float* __restrict__ xs2T, float* __restrict__ xd2T,
    float* __restrict__ es_embP, float* __restrict__ ed_embP,
    float* __restrict__ norms, float* __restrict__ dotM,
    float* __restrict__ stats, float* __restrict__ stats2) {
    __shared__ __align__(16) float As[64][68];   // [d][i] (gram path only)
    __shared__ __align__(16) float Bs[64][68];   // [d][j]
    int t = threadIdx.x;

    if (blockIdx.x >= 528) {
        int eb = blockIdx.x - 528;
        if (eb < 512) {
            // ---- node path: norms + es_emb/ed_emb (wave per node) ----
            if (eb < 2) {
                float* p = eb ? stats2 : stats;
                ((float4*)p)[t] = make_float4(0.f, 0.f, 0.f, 0.f);
            }
            int wid = t >> 6, lane = t & 63;
            int node = eb * 4 + wid;
            float e = emb[node * D_EMB + lane];
            float s2 = wave_sum(e * e);
            float esE = wave_sum(e * a_src[D_EMB + lane]);
            float edE = wave_sum(e * a_dst[D_EMB + lane]);
            if (lane == 0) {
                norms[node] = sqrtf(s2);
                es_embP[node] = esE;
                ed_embP[node] = edE;
            }
        } else {
            // ---- x path: xs/xd = bs + Sum_t x*w ----
            __shared__ float cws[5], cwd[5], cbs[2];
            if (t < 12) {
                int which = (t < 5 || t == 10) ? 0 : 1;
                const float* av = which ? a_dst : a_src;
                const float* sp;
                int stride;
                if (t < 10) { int tt = (t < 5) ? t : t - 5; sp = W + tt; stride = T_WIN; }
                else        { sp = Wb; stride = 1; }
                float acc = 0.f;
                for (int d = 0; d < D_EMB; d++) acc += sp[d * stride] * av[d];
                if (t < 5)       cws[t] = acc;
                else if (t < 10) cwd[t - 5] = acc;
                else             cbs[t - 10] = acc;
            }
            __syncthreads();
            float ws0 = cws[0], ws1 = cws[1], ws2 = cws[2], ws3 = cws[3], ws4 = cws[4];
            float wd0 = cwd[0], wd1 = cwd[1], wd2 = cwd[2], wd3 = cwd[3], wd4 = cwd[4];
            float bss = cbs[0], bsd = cbs[1];
            int base = (eb - 512) * 1024;
#pragma unroll
            for (int r = 0; r < 4; r++) {
                int item = base + 256 * r + t;
                const float* xp = x + (size_t)item * T_WIN;
                float x0 = xp[0], x1 = xp[1], x2 = xp[2], x3 = xp[3], x4 = xp[4];
                xs2T[item] = bss + x0 * ws0 + x1 * ws1 + x2 * ws2 + x3 * ws3 + x4 * ws4;
                xd2T[item] = bsd + x0 * wd0 + x1 * wd1 + x2 * wd2 + x3 * wd3 + x4 * wd4;
            }
        }
        return;
    }

    // ---- gram path: raw Gram tile, symmetric write (dot exactly symmetric)
    int g = blockIdx.x;                          // 0..527
    int a = (int)((sqrtf(8.f * g + 1.f) - 1.f) * 0.5f);
    while ((a + 1) * (a + 2) / 2 <= g) a++;
    while (a * (a + 1) / 2 > g) a--;
    int bq = g - a * (a + 1) / 2;                // 0..a
    int i0 = a * 64, j0 = bq * 64;

    {
        int r = t >> 2, c0 = t & 3;
        const float4* srcA = (const float4*)(emb + (size_t)(i0 + r) * D_EMB);
        const float4* srcB = (const float4*)(emb + (size_t)(j0 + r) * D_EMB);
#pragma unroll
        for (int k = 0; k < 4; k++) {
            int f4 = c0 + 4 * k;
            float4 v = srcA[f4];
            int d = 4 * f4;
            As[d][r] = v.x; As[d + 1][r] = v.y; As[d + 2][r] = v.z; As[d + 3][r] = v.w;
            float4 w = srcB[f4];
            Bs[d][r] = w.x; Bs[d + 1][r] = w.y; Bs[d + 2][r] = w.z; Bs[d + 3][r] = w.w;
        }
    }
    __syncthreads();

    int ti = t & 15, tj = t >> 4;
    float acc[4][4] = {};
#pragma unroll
    for (int d = 0; d < 64; d++) {
        float4 av = *(const float4*)&As[d][4 * ti];
        float4 bv = *(const float4*)&Bs[d][4 * tj];
        acc[0][0] += av.x * bv.x; acc[0][1] += av.x * bv.y; acc[0][2] += av.x * bv.z; acc[0][3] += av.x * bv.w;
        acc[1][0] += av.y * bv.x; acc[1][1] += av.y * bv.y; acc[1][2] += av.y * bv.z; acc[1][3] += av.y * bv.w;
        acc[2][0] += av.z * bv.x; acc[2][1] += av.z * bv.y; acc[2][2] += av.z * bv.z; acc[2][3] += av.z * bv.w;
        acc[3][0] += av.w * bv.x; acc[3][1] += av.w * bv.y; acc[3][2] += av.w * bv.z; acc[3][3] += av.w * bv.w;
    }

#pragma unroll
    for (int r = 0; r < 4; r++) {
        float4 o;
        o.x = acc[r][0]; o.y = acc[r][1]; o.z = acc[r][2]; o.w = acc[r][3];
        int i = i0 + 4 * ti + r;
        *(float4*)(dotM + (size_t)i * N_NODES + j0 + 4 * tj) = o;
        dotM[(size_t)(j0 + 4 * tj + 0) * N_NODES + i] = o.x;
        dotM[(size_t)(j0 + 4 * tj + 1) * N_NODES + i] = o.y;
        dotM[(size_t)(j0 + 4 * tj + 2) * N_NODES + i] = o.z;
        dotM[(size_t)(j0 + 4 * tj + 3) * N_NODES + i] = o.w;
    }
}

// ---------------- K2: top-21 selection — wave-pair split, on-the-fly norm ---
// [R5/R7 form. R9 post-mortem: 4-way split raised total bitonic-sort flush
//  work (sort count dominates, not scan length) — 2-way is the sweet spot.]
__global__ __launch_bounds__(256) void k_select(
    const float* __restrict__ dotM, const float* __restrict__ norms,
    int* __restrict__ idxT) {
    __shared__ u64 candbuf[4][128];
    __shared__ u64 mbuf[2][64];
    int tid = threadIdx.x;
    int wid = tid >> 6, lane = tid & 63;
    int pair = wid >> 1;                 // row within block (0..1)
    int half = wid & 1;                  // 0: j<1024, 1: j>=1024
    int i = blockIdx.x * 2 + pair;
    int jbase = half * (N_NODES / 2);
    const float* row = dotM + (size_t)i * N_NODES + jbase;
    u64* buf = candbuf[wid];
    float ni = norms[i];

    u64 a = 0;
    u64 t = 0;
    int cnt = 0;
    float vcur = row[lane];
    float ncur = norms[jbase + lane];

#pragma unroll 1
    for (int c = 0; c < N_NODES / 128; c++) {   // 16 chunks of 64
        int j = c * 64 + lane;
        float dv = vcur, nv = ncur;
        if (c < N_NODES / 128 - 1) {
            vcur = row[j + 64];
            ncur = norms[jbase + j + 64];
        }
        float v = dv / (ni * nv);
        unsigned u = __float_as_uint(v);
        u = (u & 0x80000000u) ? ~u : (u | 0x80000000u);
        u64 key = ((u64)u << 32) | (unsigned)(~(j + jbase));
        unsigned long long ball = __ballot(key > t);
        if (ball) {
            int ofs = __popcll(ball & ((1ull << lane) - 1ull));
            if (key > t) buf[cnt + ofs] = key;
            cnt += (int)__popcll(ball);
            if (cnt >= 64) {
                u64 nk = buf[lane];
                nk = bitonic_sort64_desc(nk, lane);
                a = bitonic_merge_top64(a, nk, lane);
                t = __shfl(a, 20, 64);
                int rem = cnt - 64;
                u64 mv = (lane < rem) ? buf[64 + lane] : 0;
                if (lane < rem) buf[lane] = mv;
                cnt = rem;
            }
        }
    }
    while (cnt > 0) {
        int take = cnt < 64 ? cnt : 64;
        u64 nk = (lane < take) ? buf[lane] : 0;
        nk = bitonic_sort64_desc(nk, lane);
        a = bitonic_merge_top64(a, nk, lane);
        t = __shfl(a, 20, 64);
        int rem = cnt - take;
        u64 mv = (lane < rem) ? buf[take + lane] : 0;
        if (lane < rem) buf[lane] = mv;
        cnt = rem;
    }

    // pair merge: upper wave publishes its sorted top-64; lower wave merges
    if (half) mbuf[pair][lane] = a;
    __syncthreads();
    if (!half) {
        u64 bv = mbuf[pair][lane];
        a = bitonic_merge_top64(a, bv, lane);
        if (lane < TOPK) idxT[lane * N_NODES + i] = (int)(~(unsigned)a);
    }
}

// ---------------- K3: k_alpha — softmax from decomposed es/ed ---------------
__global__ __launch_bounds__(256) void k_alpha(
    const int* __restrict__ idxT, const float* __restrict__ xs2T,
    const float* __restrict__ xd2T, const float* __restrict__ es_embP,
    const float* __restrict__ ed_embP, float* __restrict__ alphaT) {
    __shared__ float sed[N_NODES];   // 8 KB
    int g = blockIdx.x;
    int b = g & 31;
    int i0 = (g >> 5) * 256;
    int t = threadIdx.x;

    {
        const float4* sxd = (const float4*)(xd2T + (size_t)b * N_NODES);
        const float4* sde = (const float4*)(ed_embP);
        float4* dst = (float4*)sed;
#pragma unroll
        for (int q = 0; q < 2; q++) {
            int idx = t + 256 * q;
            float4 u = sxd[idx];
            float4 v = sde[idx];
            dst[idx] = make_float4(u.x + v.x, u.y + v.y, u.z + v.z, u.w + v.w);
        }
    }
    __syncthreads();

    int i = i0 + t;
    float es = xs2T[(size_t)b * N_NODES + i] + es_embP[i];
    float ev[TOPK];
    float m = -3e38f;
#pragma unroll
    for (int k = 0; k < TOPK; k++) {
        int jk = idxT[k * N_NODES + i];
        float e = es + sed[jk];
        e = e > 0.f ? e : NEG_SLOPE * e;
        ev[k] = e;
        m = fmaxf(m, e);
    }
    float s = 0.f;
#pragma unroll
    for (int k = 0; k < TOPK; k++) {
        ev[k] = __expf(ev[k] - m);
        s += ev[k];
    }
    float inv = 1.0f / s;
#pragma unroll
    for (int k = 0; k < TOPK; k++)
        alphaT[((size_t)b * TOPK + k) * N_NODES + i] = ev[k] * inv;
}

// ---------------- K4: message passing — b128 h-tile, bf16 obufT -------------
// [R7: hts[2048][4] 32 KB -> one ds_read_b128/neighbor; 4 blocks/CU.]
// [R10: obufT stored as bf16 ushort4 (RNE) — halves the 16 MB round-trip.
//  Stats stay f32 from pre-quantized o. Threshold 0.224, current 0.0039.]
__global__ __launch_bounds__(256, 4) void k_msg(
    const float* __restrict__ x, const float* __restrict__ W,
    const float* __restrict__ Wb, const int* __restrict__ idxT,
    const float* __restrict__ alphaT, const float* __restrict__ emb,
    u16* __restrict__ obufT, float* __restrict__ stats,
    float* __restrict__ stats2) {
    __shared__ __align__(16) float hts[N_NODES][4];   // 32 KB, b128 rows
    __shared__ float sred[2][4][4];

    int g = blockIdx.x;                        // 512 = 32 b x 16 c
    int b = (g & 7) + 8 * ((g >> 3) & 3);      // XCD-local batches
    int c = g >> 5;
    int d0 = c * 4;
    int t = threadIdx.x;
    int wid = t >> 6, lane = t & 63;

    // ---- build h-tile from x ----
    float wc[4][T_WIN], wb4[4];
#pragma unroll
    for (int q = 0; q < 4; q++) {
        wb4[q] = Wb[d0 + q];
#pragma unroll
        for (int tt = 0; tt < T_WIN; tt++) wc[q][tt] = W[(d0 + q) * T_WIN + tt];
    }
    const float* xb = x + (size_t)b * N_NODES * T_WIN;
#pragma unroll
    for (int r = 0; r < 8; r++) {
        int row = t + 256 * r;
        const float* xr = xb + row * T_WIN;
        float x0 = xr[0], x1 = xr[1], x2 = xr[2], x3 = xr[3], x4 = xr[4];
        float h0 = wb4[0] + x0 * wc[0][0] + x1 * wc[0][1] + x2 * wc[0][2] + x3 * wc[0][3] + x4 * wc[0][4];
        float h1 = wb4[1] + x0 * wc[1][0] + x1 * wc[1][1] + x2 * wc[1][2] + x3 * wc[1][3] + x4 * wc[1][4];
        float h2 = wb4[2] + x0 * wc[2][0] + x1 * wc[2][1] + x2 * wc[2][2] + x3 * wc[2][3] + x4 * wc[2][4];
        float h3 = wb4[3] + x0 * wc[3][0] + x1 * wc[3][1] + x2 * wc[3][2] + x3 * wc[3][3] + x4 * wc[3][4];
        *(float4*)&hts[row][0] = make_float4(h0, h1, h2, h3);
    }
    __syncthreads();

    // ---- gather: 2048 items, 8 per thread ----
    float sacc[4] = {0.f, 0.f, 0.f, 0.f};
    float sacc2[4] = {0.f, 0.f, 0.f, 0.f};
    const float* aT = alphaT + (size_t)b * TOPK * N_NODES;
#pragma unroll 1
    for (int r = 0; r < 8; r++) {
        int i = 256 * r + t;
        float4 z = make_float4(0.f, 0.f, 0.f, 0.f);
#pragma unroll
        for (int k = 0; k < TOPK; k++) {
            int jk = idxT[k * N_NODES + i];          // coalesced, L2-resident
            float a = aT[(size_t)k * N_NODES + i];   // coalesced
            float4 h4 = *(const float4*)&hts[jk][0]; // one ds_read_b128
            z.x = fmaf(a, h4.x, z.x);
            z.y = fmaf(a, h4.y, z.y);
            z.z = fmaf(a, h4.z, z.z);
            z.w = fmaf(a, h4.w, z.w);
        }
        float4 e4 = *(const float4*)(emb + (size_t)i * D_EMB + d0);
        float4 o;
        o.x = fmaxf(z.x, 0.f) * e4.x;
        o.y = fmaxf(z.y, 0.f) * e4.y;
        o.z = fmaxf(z.z, 0.f) * e4.z;
        o.w = fmaxf(z.w, 0.f) * e4.w;
        ushort4 st;
        st.x = f2bf(o.x); st.y = f2bf(o.y); st.z = f2bf(o.z); st.w = f2bf(o.w);
        ((ushort4*)obufT)[((size_t)c * B_BATCH + b) * N_NODES + i] = st;
        sacc[0] += o.x; sacc[1] += o.y; sacc[2] += o.z; sacc[3] += o.w;
        sacc2[0] += o.x * o.x; sacc2[1] += o.y * o.y;
        sacc2[2] += o.z * o.z; sacc2[3] += o.w * o.w;
    }

    // ---- stats partials ----
#pragma unroll
    for (int q = 0; q < 4; q++) {
        sacc[q] = wave_sum(sacc[q]);
        sacc2[q] = wave_sum(sacc2[q]);
    }
    if (lane == 0) {
#pragma unroll
        for (int q = 0; q < 4; q++) {
            sred[0][wid][q] = sacc[q];
            sred[1][wid][q] = sacc2[q];
        }
    }
    __syncthreads();
    if (t < 8) {
        int q = t & 3, which = t >> 2;
        float v = sred[which][0][q] + sred[which][1][q] + sred[which][2][q] + sred[which][3][q];
        float* dst = which ? stats2 : stats;
        atomicAdd(&dst[(d0 + q) * STATS_STRIDE], v);
    }
}

// ---------------- K5: BN apply + relu + fc — bf16 c-panel sweep -------------
__global__ __launch_bounds__(256) void k_out(
    const u16* __restrict__ obufT, const float* __restrict__ stats,
    const float* __restrict__ stats2, const float* __restrict__ gamma,
    const float* __restrict__ beta, const float* __restrict__ fc_w,
    const float* __restrict__ fc_b, float* __restrict__ out) {
    __shared__ float smean[64], sinv[64], sg[64], sb[64], sf[64];
    int t = threadIdx.x;
    int g = blockIdx.x;                 // 256 = 32 b x 8 n-chunks
    int b = g & 31, nc = g >> 5;
    int n = nc * 256 + t;
    const float invM = 1.0f / (float)BN_TOTAL;

    if (t < 64) {
        float mn = stats[t * STATS_STRIDE] * invM;
        float var = stats2[t * STATS_STRIDE] * invM - mn * mn;
        smean[t] = mn;
        sinv[t] = rsqrtf(var + EPS_BN);
        sg[t] = gamma[t]; sb[t] = beta[t]; sf[t] = fc_w[t];
    }
    __syncthreads();

    float fb = fc_b[0];
    float p = 0.f;
#pragma unroll
    for (int c = 0; c < 16; c++) {
        ushort4 h4 = ((const ushort4*)obufT)[((size_t)c * B_BATCH + b) * N_NODES + n];
        float ox = bf2f(h4.x), oy = bf2f(h4.y), oz = bf2f(h4.z), ow = bf2f(h4.w);
        int d = 4 * c;
        float v;
        v = fmaxf((ox - smean[d + 0]) * sinv[d + 0] * sg[d + 0] + sb[d + 0], 0.f); p = fmaf(v, sf[d + 0], p);
        v = fmaxf((oy - smean[d + 1]) * sinv[d + 1] * sg[d + 1] + sb[d + 1], 0.f); p = fmaf(v, sf[d + 1], p);
        v = fmaxf((oz - smean[d + 2]) * sinv[d + 2] * sg[d + 2] + sb[d + 2], 0.f); p = fmaf(v, sf[d + 2], p);
        v = fmaxf((ow - smean[d + 3]) * sinv[d + 3] * sg[d + 3] + sb[d + 3], 0.f); p = fmaf(v, sf[d + 3], p);
    }
    out[b * N_NODES + n] = p + fb;
}

// ---------------- launch ----------------------------------------------------
extern "C" void kernel_launch(void* const* d_in, const int* in_sizes, int n_in,
                              void* d_out, int out_size, void* d_ws, size_t ws_size,
                              hipStream_t stream) {
    const float* x     = (const float*)d_in[0];
    const float* emb   = (const float*)d_in[1];
    const float* W     = (const float*)d_in[2];
    const float* Wb    = (const float*)d_in[3];
    const float* a_src = (const float*)d_in[4];
    const float* a_dst = (const float*)d_in[5];
    const float* gamma = (const float*)d_in[6];
    const float* beta  = (const float*)d_in[7];
    const float* fc_w  = (const float*)d_in[8];
    const float* fc_b  = (const float*)d_in[9];
    float* out = (float*)d_out;

    char* ws = (char*)d_ws;
    float* stats   = (float*)(ws + 0);            // 4 KB
    float* stats2  = (float*)(ws + 4096);         // 4 KB
    int*   idxT    = (int*)  (ws + 8192);         // 172032 B
    float* norms   = (float*)(ws + 180224);       // 8 KB
    float* es_embP = (float*)(ws + 188416);       // 8 KB
    float* ed_embP = (float*)(ws + 196608);       // 8 KB
    float* xs2T    = (float*)(ws + 204800);       // 256 KB [b][n]
    float* xd2T    = (float*)(ws + 466944);       // 256 KB [b][n]
    float* alphaT  = (float*)(ws + 729088);       // 5505024 B [b][k][i]
    float* dotM    = (float*)(ws + 6234112);      // 16 MB — aliased with obufT
    u16*   obufT   = (u16*)dotM;                  // 8.4 MB bf16 (dotM dead after k_select)
    // total: 23,011,328 bytes

    k_preg<<<1104, 256, 0, stream>>>(x, W, Wb, a_src, a_dst, emb,
                                     xs2T, xd2T, es_embP, ed_embP, norms,
                                     dotM, stats, stats2);
    k_select<<<N_NODES / 2, 256, 0, stream>>>(dotM, norms, idxT);
    k_alpha<<<256, 256, 0, stream>>>(idxT, xs2T, xd2T, es_embP, ed_embP, alphaT);
    k_msg<<<512, 256, 0, stream>>>(x, W, Wb, idxT, alphaT, emb, obufT, stats, stats2);
    k_out<<<256, 256, 0, stream>>>(obufT, stats, stats2, gamma, beta, fc_w, fc_b, out);
}

// Round 14
// 127.134 us; speedup vs baseline: 1.0535x; 1.0117x over previous
//
#include <hip/hip_runtime.h>
#include <hip/hip_fp16.h>
#include <math.h>

#define N_NODES 2048
#define T_WIN 5
#define D_EMB 64
#define TOPK 21
#define B_BATCH 32
#define BN_TOTAL (B_BATCH * N_NODES)   // 65536
#define EPS_BN 1e-5f
#define NEG_SLOPE 0.2f
#define STATS_STRIDE 16

typedef unsigned long long u64;
typedef unsigned short u16;
typedef unsigned int u32;

// ---------------- wave-level helpers (wave = 64 on gfx950) ----------------
__device__ __forceinline__ float wave_sum(float v) {
#pragma unroll
    for (int off = 32; off > 0; off >>= 1) v += __shfl_xor(v, off, 64);
    return v;
}

__device__ __forceinline__ u64 max64(u64 a, u64 b) { return a > b ? a : b; }
__device__ __forceinline__ u64 min64(u64 a, u64 b) { return a < b ? a : b; }

__device__ __forceinline__ u64 bitonic_sort64_desc(u64 key, int lane) {
#pragma unroll
    for (int k = 2; k <= 64; k <<= 1) {
#pragma unroll
        for (int j = k >> 1; j >= 1; j >>= 1) {
            u64 pk = __shfl_xor(key, j, 64);
            bool dirDesc = ((lane & k) == 0);
            bool keepMax = (((lane & j) == 0) == dirDesc);
            key = keepMax ? max64(key, pk) : min64(key, pk);
        }
    }
    return key;
}

__device__ __forceinline__ u64 bitonic_merge_top64(u64 a, u64 b, int lane) {
    u64 br = __shfl(b, 63 - lane, 64);
    u64 c = max64(a, br);
#pragma unroll
    for (int j = 32; j >= 1; j >>= 1) {
        u64 pk = __shfl_xor(c, j, 64);
        bool keepMax = ((lane & j) == 0);
        c = keepMax ? max64(c, pk) : min64(c, pk);
    }
    return c;
}

// bf16 round-to-nearest-even pack/unpack (obufT; measured ~300x worst-case
// amplification through BN 1/sigma + fc — 0.0625 absmax vs 0.224 threshold)
__device__ __forceinline__ u16 f2bf(float f) {
    unsigned u = __float_as_uint(f);
    return (u16)((u + 0x7FFFu + ((u >> 16) & 1u)) >> 16);
}
__device__ __forceinline__ float bf2f(u16 h) {
    return __uint_as_float((unsigned)h << 16);
}

// ---------------- K1: k_preg — fused {raw Gram tiles} + {edge precompute} ---
// [R7: gram writes RAW dots, /(ni*nj) in k_select — bit-identical keys.]
// [R8: grid.sync cross-XCD handoff FAILED; kernel boundaries only fence.]
// [R9: LDS-transpose epilogue had 8-way conflicts — direct mirror writes.]
// [R13: R11/R12 failures were a WORKSPACE OVERLAP (paT under-sized by 2x,
//  upper half aliased obufT) — layout re-derived from element counts.]
// [R14: R13 aborted with core dump, no fault message; full bounds re-audit
//  clean — resubmitted unchanged as an infra-flake retest.]
__global__ __launch_bounds__(256) void k_preg(
    const float* __restrict__ x, const float* __restrict__ W,
    const float* __restrict__ Wb, const float* __restrict__ a_src,
    const float* __restrict__ a_dst, const float* __restrict__ emb,
    float* __restrict__ xs2T, float* __restrict__ xd2T,
    float* __restrict__ es_embP, float* __restrict__ ed_embP,
    float* __restrict__ norms, float* __restrict__ dotM,
    float* __restrict__ stats, float* __restrict__ stats2) {
    __shared__ __align__(16) float As[64][68];   // [d][i] (gram path only)
    __shared__ __align__(16) float Bs[64][68];   // [d][j]
    int t = threadIdx.x;

    if (blockIdx.x >= 528) {
        int eb = blockIdx.x - 528;
        if (eb < 512) {
            // ---- node path: norms + es_emb/ed_emb (wave per node) ----
            if (eb < 2) {
                float* p = eb ? stats2 : stats;
                ((float4*)p)[t] = make_float4(0.f, 0.f, 0.f, 0.f);
            }
            int wid = t >> 6, lane = t & 63;
            int node = eb * 4 + wid;
            float e = emb[node * D_EMB + lane];
            float s2 = wave_sum(e * e);
            float esE = wave_sum(e * a_src[D_EMB + lane]);
            float edE = wave_sum(e * a_dst[D_EMB + lane]);
            if (lane == 0) {
                norms[node] = sqrtf(s2);
                es_embP[node] = esE;
                ed_embP[node] = edE;
            }
        } else {
            // ---- x path: xs/xd = bs + Sum_t x*w ----
            __shared__ float cws[5], cwd[5], cbs[2];
            if (t < 12) {
                int which = (t < 5 || t == 10) ? 0 : 1;
                const float* av = which ? a_dst : a_src;
                const float* sp;
                int stride;
                if (t < 10) { int tt = (t < 5) ? t : t - 5; sp = W + tt; stride = T_WIN; }
                else        { sp = Wb; stride = 1; }
                float acc = 0.f;
                for (int d = 0; d < D_EMB; d++) acc += sp[d * stride] * av[d];
                if (t < 5)       cws[t] = acc;
                else if (t < 10) cwd[t - 5] = acc;
                else             cbs[t - 10] = acc;
            }
            __syncthreads();
            float ws0 = cws[0], ws1 = cws[1], ws2 = cws[2], ws3 = cws[3], ws4 = cws[4];
            float wd0 = cwd[0], wd1 = cwd[1], wd2 = cwd[2], wd3 = cwd[3], wd4 = cwd[4];
            float bss = cbs[0], bsd = cbs[1];
            int base = (eb - 512) * 1024;
#pragma unroll
            for (int r = 0; r < 4; r++) {
                int item = base + 256 * r + t;
                const float* xp = x + (size_t)item * T_WIN;
                float x0 = xp[0], x1 = xp[1], x2 = xp[2], x3 = xp[3], x4 = xp[4];
                xs2T[item] = bss + x0 * ws0 + x1 * ws1 + x2 * ws2 + x3 * ws3 + x4 * ws4;
                xd2T[item] = bsd + x0 * wd0 + x1 * wd1 + x2 * wd2 + x3 * wd3 + x4 * wd4;
            }
        }
        return;
    }

    // ---- gram path: raw Gram tile, symmetric write (dot exactly symmetric)
    int g = blockIdx.x;                          // 0..527
    int a = (int)((sqrtf(8.f * g + 1.f) - 1.f) * 0.5f);
    while ((a + 1) * (a + 2) / 2 <= g) a++;
    while (a * (a + 1) / 2 > g) a--;
    int bq = g - a * (a + 1) / 2;                // 0..a
    int i0 = a * 64, j0 = bq * 64;

    {
        int r = t >> 2, c0 = t & 3;
        const float4* srcA = (const float4*)(emb + (size_t)(i0 + r) * D_EMB);
        const float4* srcB = (const float4*)(emb + (size_t)(j0 + r) * D_EMB);
#pragma unroll
        for (int k = 0; k < 4; k++) {
            int f4 = c0 + 4 * k;
            float4 v = srcA[f4];
            int d = 4 * f4;
            As[d][r] = v.x; As[d + 1][r] = v.y; As[d + 2][r] = v.z; As[d + 3][r] = v.w;
            float4 w = srcB[f4];
            Bs[d][r] = w.x; Bs[d + 1][r] = w.y; Bs[d + 2][r] = w.z; Bs[d + 3][r] = w.w;
        }
    }
    __syncthreads();

    int ti = t & 15, tj = t >> 4;
    float acc[4][4] = {};
#pragma unroll
    for (int d = 0; d < 64; d++) {
        float4 av = *(const float4*)&As[d][4 * ti];
        float4 bv = *(const float4*)&Bs[d][4 * tj];
        acc[0][0] += av.x * bv.x; acc[0][1] += av.x * bv.y; acc[0][2] += av.x * bv.z; acc[0][3] += av.x * bv.w;
        acc[1][0] += av.y * bv.x; acc[1][1] += av.y * bv.y; acc[1][2] += av.y * bv.z; acc[1][3] += av.y * bv.w;
        acc[2][0] += av.z * bv.x; acc[2][1] += av.z * bv.y; acc[2][2] += av.z * bv.z; acc[2][3] += av.z * bv.w;
        acc[3][0] += av.w * bv.x; acc[3][1] += av.w * bv.y; acc[3][2] += av.w * bv.z; acc[3][3] += av.w * bv.w;
    }

#pragma unroll
    for (int r = 0; r < 4; r++) {
        float4 o;
        o.x = acc[r][0]; o.y = acc[r][1]; o.z = acc[r][2]; o.w = acc[r][3];
        int i = i0 + 4 * ti + r;
        *(float4*)(dotM + (size_t)i * N_NODES + j0 + 4 * tj) = o;
        dotM[(size_t)(j0 + 4 * tj + 0) * N_NODES + i] = o.x;
        dotM[(size_t)(j0 + 4 * tj + 1) * N_NODES + i] = o.y;
        dotM[(size_t)(j0 + 4 * tj + 2) * N_NODES + i] = o.z;
        dotM[(size_t)(j0 + 4 * tj + 3) * N_NODES + i] = o.w;
    }
}

// ---------------- K2: top-21 selection — wave-pair split, on-the-fly norm ---
// [R5/R7 form; R9: 2-way split is the sweet spot (flush count dominates).]
__global__ __launch_bounds__(256) void k_select(
    const float* __restrict__ dotM, const float* __restrict__ norms,
    int* __restrict__ idxT) {
    __shared__ u64 candbuf[4][128];
    __shared__ u64 mbuf[2][64];
    int tid = threadIdx.x;
    int wid = tid >> 6, lane = tid & 63;
    int pair = wid >> 1;                 // row within block (0..1)
    int half = wid & 1;                  // 0: j<1024, 1: j>=1024
    int i = blockIdx.x * 2 + pair;
    int jbase = half * (N_NODES / 2);
    const float* row = dotM + (size_t)i * N_NODES + jbase;
    u64* buf = candbuf[wid];
    float ni = norms[i];

    u64 a = 0;
    u64 t = 0;
    int cnt = 0;
    float vcur = row[lane];
    float ncur = norms[jbase + lane];

#pragma unroll 1
    for (int c = 0; c < N_NODES / 128; c++) {   // 16 chunks of 64
        int j = c * 64 + lane;
        float dv = vcur, nv = ncur;
        if (c < N_NODES / 128 - 1) {
            vcur = row[j + 64];
            ncur = norms[jbase + j + 64];
        }
        float v = dv / (ni * nv);
        unsigned u = __float_as_uint(v);
        u = (u & 0x80000000u) ? ~u : (u | 0x80000000u);
        u64 key = ((u64)u << 32) | (unsigned)(~(j + jbase));
        unsigned long long ball = __ballot(key > t);
        if (ball) {
            int ofs = __popcll(ball & ((1ull << lane) - 1ull));
            if (key > t) buf[cnt + ofs] = key;
            cnt += (int)__popcll(ball);
            if (cnt >= 64) {
                u64 nk = buf[lane];
                nk = bitonic_sort64_desc(nk, lane);
                a = bitonic_merge_top64(a, nk, lane);
                t = __shfl(a, 20, 64);
                int rem = cnt - 64;
                u64 mv = (lane < rem) ? buf[64 + lane] : 0;
                if (lane < rem) buf[lane] = mv;
                cnt = rem;
            }
        }
    }
    while (cnt > 0) {
        int take = cnt < 64 ? cnt : 64;
        u64 nk = (lane < take) ? buf[lane] : 0;
        nk = bitonic_sort64_desc(nk, lane);
        a = bitonic_merge_top64(a, nk, lane);
        t = __shfl(a, 20, 64);
        int rem = cnt - take;
        u64 mv = (lane < rem) ? buf[take + lane] : 0;
        if (lane < rem) buf[lane] = mv;
        cnt = rem;
    }

    // pair merge: upper wave publishes its sorted top-64; lower wave merges
    if (half) mbuf[pair][lane] = a;
    __syncthreads();
    if (!half) {
        u64 bv = mbuf[pair][lane];
        a = bitonic_merge_top64(a, bv, lane);
        if (lane < TOPK) idxT[lane * N_NODES + i] = (int)(~(unsigned)a);
    }
}

// ---------------- K3: k_alpha — softmax -> packed paT[b][k][i]={idx,a-f16} --
// paT u32 = (jk<<16) | f16(alpha): ONE dword/neighbor in k_msg (was 21 idx
// + 21 alpha loads) and idxT leaves k_msg's working set. Element count same
// as alphaT (5,505,024 B). alpha-through-f16 adds ~0.02 absmax (budget .224).
__global__ __launch_bounds__(256) void k_alpha(
    const int* __restrict__ idxT, const float* __restrict__ xs2T,
    const float* __restrict__ xd2T, const float* __restrict__ es_embP,
    const float* __restrict__ ed_embP, u32* __restrict__ paT) {
    __shared__ float sed[N_NODES];   // 8 KB
    int g = blockIdx.x;
    int b = g & 31;
    int i0 = (g >> 5) * 256;
    int t = threadIdx.x;

    {
        const float4* sxd = (const float4*)(xd2T + (size_t)b * N_NODES);
        const float4* sde = (const float4*)(ed_embP);
        float4* dst = (float4*)sed;
#pragma unroll
        for (int q = 0; q < 2; q++) {
            int idx = t + 256 * q;
            float4 u = sxd[idx];
            float4 v = sde[idx];
            dst[idx] = make_float4(u.x + v.x, u.y + v.y, u.z + v.z, u.w + v.w);
        }
    }
    __syncthreads();

    int i = i0 + t;
    float es = xs2T[(size_t)b * N_NODES + i] + es_embP[i];
    int jk[TOPK];
    float ev[TOPK];
    float m = -3e38f;
#pragma unroll
    for (int k = 0; k < TOPK; k++) {
        jk[k] = idxT[k * N_NODES + i];
        float e = es + sed[jk[k]];
        e = e > 0.f ? e : NEG_SLOPE * e;
        ev[k] = e;
        m = fmaxf(m, e);
    }
    float s = 0.f;
#pragma unroll
    for (int k = 0; k < TOPK; k++) {
        ev[k] = __expf(ev[k] - m);
        s += ev[k];
    }
    float inv = 1.0f / s;
#pragma unroll
    for (int k = 0; k < TOPK; k++) {
        u16 ah = __half_as_ushort(__float2half_rn(ev[k] * inv));
        paT[((size_t)b * TOPK + k) * N_NODES + i] = ((u32)jk[k] << 16) | (u32)ah;
    }
}

// ---------------- K4: message passing — f32 gather, packed pa loads ---------
// [R7: hts[2048][4] f32 32 KB -> one ds_read_b128/neighbor; 4 blocks/CU.]
// [R10: obufT bf16 (halves the 16 MB round-trip).]
// [R13/R14: paT u32 -> 21 VMEM instrs/item (was 42); alpha via v_cvt_f32_f16;
//  gather math stays f32 scalar fmaf — verified R10 path.]
__global__ __launch_bounds__(256, 4) void k_msg(
    const float* __restrict__ x, const float* __restrict__ W,
    const float* __restrict__ Wb, const u32* __restrict__ paT,
    const float* __restrict__ emb, u16* __restrict__ obufT,
    float* __restrict__ stats, float* __restrict__ stats2) {
    __shared__ __align__(16) float hts[N_NODES][4];   // 32 KB, b128 rows
    __shared__ float sred[2][4][4];

    int g = blockIdx.x;                        // 512 = 32 b x 16 c
    int b = (g & 7) + 8 * ((g >> 3) & 3);      // XCD-local batches
    int c = g >> 5;
    int d0 = c * 4;
    int t = threadIdx.x;
    int wid = t >> 6, lane = t & 63;

    // ---- build h-tile from x ----
    float wc[4][T_WIN], wb4[4];
#pragma unroll
    for (int q = 0; q < 4; q++) {
        wb4[q] = Wb[d0 + q];
#pragma unroll
        for (int tt = 0; tt < T_WIN; tt++) wc[q][tt] = W[(d0 + q) * T_WIN + tt];
    }
    const float* xb = x + (size_t)b * N_NODES * T_WIN;
#pragma unroll
    for (int r = 0; r < 8; r++) {
        int row = t + 256 * r;
        const float* xr = xb + row * T_WIN;
        float x0 = xr[0], x1 = xr[1], x2 = xr[2], x3 = xr[3], x4 = xr[4];
        float h0 = wb4[0] + x0 * wc[0][0] + x1 * wc[0][1] + x2 * wc[0][2] + x3 * wc[0][3] + x4 * wc[0][4];
        float h1 = wb4[1] + x0 * wc[1][0] + x1 * wc[1][1] + x2 * wc[1][2] + x3 * wc[1][3] + x4 * wc[1][4];
        float h2 = wb4[2] + x0 * wc[2][0] + x1 * wc[2][1] + x2 * wc[2][2] + x3 * wc[2][3] + x4 * wc[2][4];
        float h3 = wb4[3] + x0 * wc[3][0] + x1 * wc[3][1] + x2 * wc[3][2] + x3 * wc[3][3] + x4 * wc[3][4];
        *(float4*)&hts[row][0] = make_float4(h0, h1, h2, h3);
    }
    __syncthreads();

    // ---- gather: 2048 items, 8 per thread ----
    float sacc[4] = {0.f, 0.f, 0.f, 0.f};
    float sacc2[4] = {0.f, 0.f, 0.f, 0.f};
    const u32* pb = paT + (size_t)b * TOPK * N_NODES;
#pragma unroll 1
    for (int r = 0; r < 8; r++) {
        int i = 256 * r + t;
        float4 z = make_float4(0.f, 0.f, 0.f, 0.f);
#pragma unroll
        for (int k = 0; k < TOPK; k++) {
            u32 pa = pb[(size_t)k * N_NODES + i];    // coalesced, 1 dword
            int jk = (int)(pa >> 16);
            float a = __half2float(__ushort_as_half((u16)(pa & 0xFFFFu)));
            float4 h4 = *(const float4*)&hts[jk][0]; // one ds_read_b128
            z.x = fmaf(a, h4.x, z.x);
            z.y = fmaf(a, h4.y, z.y);
            z.z = fmaf(a, h4.z, z.z);
            z.w = fmaf(a, h4.w, z.w);
        }
        float4 e4 = *(const float4*)(emb + (size_t)i * D_EMB + d0);
        float4 o;
        o.x = fmaxf(z.x, 0.f) * e4.x;
        o.y = fmaxf(z.y, 0.f) * e4.y;
        o.z = fmaxf(z.z, 0.f) * e4.z;
        o.w = fmaxf(z.w, 0.f) * e4.w;
        ushort4 st;
        st.x = f2bf(o.x); st.y = f2bf(o.y); st.z = f2bf(o.z); st.w = f2bf(o.w);
        ((ushort4*)obufT)[((size_t)c * B_BATCH + b) * N_NODES + i] = st;
        sacc[0] += o.x; sacc[1] += o.y; sacc[2] += o.z; sacc[3] += o.w;
        sacc2[0] += o.x * o.x; sacc2[1] += o.y * o.y;
        sacc2[2] += o.z * o.z; sacc2[3] += o.w * o.w;
    }

    // ---- stats partials ----
#pragma unroll
    for (int q = 0; q < 4; q++) {
        sacc[q] = wave_sum(sacc[q]);
        sacc2[q] = wave_sum(sacc2[q]);
    }
    if (lane == 0) {
#pragma unroll
        for (int q = 0; q < 4; q++) {
            sred[0][wid][q] = sacc[q];
            sred[1][wid][q] = sacc2[q];
        }
    }
    __syncthreads();
    if (t < 8) {
        int q = t & 3, which = t >> 2;
        float v = sred[which][0][q] + sred[which][1][q] + sred[which][2][q] + sred[which][3][q];
        float* dst = which ? stats2 : stats;
        atomicAdd(&dst[(d0 + q) * STATS_STRIDE], v);
    }
}

// ---------------- K5: BN apply + relu + fc — bf16 c-panel sweep -------------
__global__ __launch_bounds__(256) void k_out(
    const u16* __restrict__ obufT, const float* __restrict__ stats,
    const float* __restrict__ stats2, const float* __restrict__ gamma,
    const float* __restrict__ beta, const float* __restrict__ fc_w,
    const float* __restrict__ fc_b, float* __restrict__ out) {
    __shared__ float smean[64], sinv[64], sg[64], sb[64], sf[64];
    int t = threadIdx.x;
    int g = blockIdx.x;                 // 256 = 32 b x 8 n-chunks
    int b = g & 31, nc = g >> 5;
    int n = nc * 256 + t;
    const float invM = 1.0f / (float)BN_TOTAL;

    if (t < 64) {
        float mn = stats[t * STATS_STRIDE] * invM;
        float var = stats2[t * STATS_STRIDE] * invM - mn * mn;
        smean[t] = mn;
        sinv[t] = rsqrtf(var + EPS_BN);
        sg[t] = gamma[t]; sb[t] = beta[t]; sf[t] = fc_w[t];
    }
    __syncthreads();

    float fb = fc_b[0];
    float p = 0.f;
#pragma unroll
    for (int c = 0; c < 16; c++) {
        ushort4 h4 = ((const ushort4*)obufT)[((size_t)c * B_BATCH + b) * N_NODES + n];
        float ox = bf2f(h4.x), oy = bf2f(h4.y), oz = bf2f(h4.z), ow = bf2f(h4.w);
        int d = 4 * c;
        float v;
        v = fmaxf((ox - smean[d + 0]) * sinv[d + 0] * sg[d + 0] + sb[d + 0], 0.f); p = fmaf(v, sf[d + 0], p);
        v = fmaxf((oy - smean[d + 1]) * sinv[d + 1] * sg[d + 1] + sb[d + 1], 0.f); p = fmaf(v, sf[d + 1], p);
        v = fmaxf((oz - smean[d + 2]) * sinv[d + 2] * sg[d + 2] + sb[d + 2], 0.f); p = fmaf(v, sf[d + 2], p);
        v = fmaxf((ow - smean[d + 3]) * sinv[d + 3] * sg[d + 3] + sb[d + 3], 0.f); p = fmaf(v, sf[d + 3], p);
    }
    out[b * N_NODES + n] = p + fb;
}

// ---------------- launch ----------------------------------------------------
extern "C" void kernel_launch(void* const* d_in, const int* in_sizes, int n_in,
                              void* d_out, int out_size, void* d_ws, size_t ws_size,
                              hipStream_t stream) {
    const float* x     = (const float*)d_in[0];
    const float* emb   = (const float*)d_in[1];
    const float* W     = (const float*)d_in[2];
    const float* Wb    = (const float*)d_in[3];
    const float* a_src = (const float*)d_in[4];
    const float* a_dst = (const float*)d_in[5];
    const float* gamma = (const float*)d_in[6];
    const float* beta  = (const float*)d_in[7];
    const float* fc_w  = (const float*)d_in[8];
    const float* fc_b  = (const float*)d_in[9];
    float* out = (float*)d_out;

    // Workspace map (re-derived from ELEMENT COUNTS):
    //   stats    [0,        4096)
    //   stats2   [4096,     8192)
    //   idxT     [8192,     180224)   21*2048*4      = 172,032
    //   norms    [180224,   188416)   2048*4         = 8,192
    //   es_embP  [188416,   196608)   2048*4         = 8,192
    //   ed_embP  [196608,   204800)   2048*4         = 8,192
    //   xs2T     [204800,   466944)   65536*4        = 262,144
    //   xd2T     [466944,   729088)   65536*4        = 262,144
    //   paT      [729088,   6234112)  32*21*2048*4   = 5,505,024
    //   dotM     [6234112,  23011328) 2048*2048*4    = 16,777,216
    //   obufT  = dotM alias (8.4 MB bf16; dotM dead after k_select)
    char* ws = (char*)d_ws;
    float* stats   = (float*)(ws + 0);
    float* stats2  = (float*)(ws + 4096);
    int*   idxT    = (int*)  (ws + 8192);
    float* norms   = (float*)(ws + 180224);
    float* es_embP = (float*)(ws + 188416);
    float* ed_embP = (float*)(ws + 196608);
    float* xs2T    = (float*)(ws + 204800);
    float* xd2T    = (float*)(ws + 466944);
    u32*   paT     = (u32*)  (ws + 729088);
    float* dotM    = (float*)(ws + 6234112);
    u16*   obufT   = (u16*)dotM;
    // total: 23,011,328 bytes

    k_preg<<<1104, 256, 0, stream>>>(x, W, Wb, a_src, a_dst, emb,
                                     xs2T, xd2T, es_embP, ed_embP, norms,
                                     dotM, stats, stats2);
    k_select<<<N_NODES / 2, 256, 0, stream>>>(dotM, norms, idxT);
    k_alpha<<<256, 256, 0, stream>>>(idxT, xs2T, xd2T, es_embP, ed_embP, paT);
    k_msg<<<512, 256, 0, stream>>>(x, W, Wb, paT, emb, obufT, stats, stats2);
    k_out<<<256, 256, 0, stream>>>(obufT, stats, stats2, gamma, beta, fc_w, fc_b, out);
}

// Round 15
// 125.989 us; speedup vs baseline: 1.0631x; 1.0091x over previous
//
#include <hip/hip_runtime.h>
#include <hip/hip_fp16.h>
#include <math.h>

#define N_NODES 2048
#define T_WIN 5
#define D_EMB 64
#define TOPK 21
#define B_BATCH 32
#define BN_TOTAL (B_BATCH * N_NODES)   // 65536
#define EPS_BN 1e-5f
#define NEG_SLOPE 0.2f
#define STATS_STRIDE 16

typedef unsigned long long u64;
typedef unsigned short u16;
typedef unsigned int u32;

// ---------------- wave-level helpers (wave = 64 on gfx950) ----------------
__device__ __forceinline__ float wave_sum(float v) {
#pragma unroll
    for (int off = 32; off > 0; off >>= 1) v += __shfl_xor(v, off, 64);
    return v;
}

__device__ __forceinline__ u64 max64(u64 a, u64 b) { return a > b ? a : b; }
__device__ __forceinline__ u64 min64(u64 a, u64 b) { return a < b ? a : b; }

__device__ __forceinline__ u64 bitonic_sort64_desc(u64 key, int lane) {
#pragma unroll
    for (int k = 2; k <= 64; k <<= 1) {
#pragma unroll
        for (int j = k >> 1; j >= 1; j >>= 1) {
            u64 pk = __shfl_xor(key, j, 64);
            bool dirDesc = ((lane & k) == 0);
            bool keepMax = (((lane & j) == 0) == dirDesc);
            key = keepMax ? max64(key, pk) : min64(key, pk);
        }
    }
    return key;
}

__device__ __forceinline__ u64 bitonic_merge_top64(u64 a, u64 b, int lane) {
    u64 br = __shfl(b, 63 - lane, 64);
    u64 c = max64(a, br);
#pragma unroll
    for (int j = 32; j >= 1; j >>= 1) {
        u64 pk = __shfl_xor(c, j, 64);
        bool keepMax = ((lane & j) == 0);
        c = keepMax ? max64(c, pk) : min64(c, pk);
    }
    return c;
}

// bf16 round-to-nearest-even pack/unpack (obufT; measured ~300x worst-case
// amplification through BN 1/sigma + fc — 0.0625 absmax vs 0.224 threshold)
__device__ __forceinline__ u16 f2bf(float f) {
    unsigned u = __float_as_uint(f);
    return (u16)((u + 0x7FFFu + ((u >> 16) & 1u)) >> 16);
}
__device__ __forceinline__ float bf2f(u16 h) {
    return __uint_as_float((unsigned)h << 16);
}

// ---------------- K1: k_preg — fused {raw Gram tiles} + {edge precompute} ---
// [R7: gram writes RAW dots, /(ni*nj) in k_select — bit-identical keys.]
// [R8: grid.sync cross-XCD handoff FAILED; kernel boundaries only fence.]
// [R9: LDS-transpose epilogue had 8-way conflicts — direct mirror writes.]
// [R13/R14: R11/R12 failures were a workspace overlap, fixed + verified.]
__global__ __launch_bounds__(256) void k_preg(
    const float* __restrict__ x, const float* __restrict__ W,
    const float* __restrict__ Wb, const float* __restrict__ a_src,
    const float* __restrict__ a_dst, const float* __restrict__ emb,
    float* __restrict__ xs2T, float* __restrict__ xd2T,
    float* __restrict__ es_embP, float* __restrict__ ed_embP,
    float* __restrict__ norms, float* __restrict__ dotM,
    float* __restrict__ stats, float* __restrict__ stats2) {
    __shared__ __align__(16) float As[64][68];   // [d][i] (gram path only)
    __shared__ __align__(16) float Bs[64][68];   // [d][j]
    int t = threadIdx.x;

    if (blockIdx.x >= 528) {
        int eb = blockIdx.x - 528;
        if (eb < 512) {
            // ---- node path: norms + es_emb/ed_emb (wave per node) ----
            if (eb < 2) {
                float* p = eb ? stats2 : stats;
                ((float4*)p)[t] = make_float4(0.f, 0.f, 0.f, 0.f);
            }
            int wid = t >> 6, lane = t & 63;
            int node = eb * 4 + wid;
            float e = emb[node * D_EMB + lane];
            float s2 = wave_sum(e * e);
            float esE = wave_sum(e * a_src[D_EMB + lane]);
            float edE = wave_sum(e * a_dst[D_EMB + lane]);
            if (lane == 0) {
                norms[node] = sqrtf(s2);
                es_embP[node] = esE;
                ed_embP[node] = edE;
            }
        } else {
            // ---- x path: xs/xd = bs + Sum_t x*w ----
            __shared__ float cws[5], cwd[5], cbs[2];
            if (t < 12) {
                int which = (t < 5 || t == 10) ? 0 : 1;
                const float* av = which ? a_dst : a_src;
                const float* sp;
                int stride;
                if (t < 10) { int tt = (t < 5) ? t : t - 5; sp = W + tt; stride = T_WIN; }
                else        { sp = Wb; stride = 1; }
                float acc = 0.f;
                for (int d = 0; d < D_EMB; d++) acc += sp[d * stride] * av[d];
                if (t < 5)       cws[t] = acc;
                else if (t < 10) cwd[t - 5] = acc;
                else             cbs[t - 10] = acc;
            }
            __syncthreads();
            float ws0 = cws[0], ws1 = cws[1], ws2 = cws[2], ws3 = cws[3], ws4 = cws[4];
            float wd0 = cwd[0], wd1 = cwd[1], wd2 = cwd[2], wd3 = cwd[3], wd4 = cwd[4];
            float bss = cbs[0], bsd = cbs[1];
            int base = (eb - 512) * 1024;
#pragma unroll
            for (int r = 0; r < 4; r++) {
                int item = base + 256 * r + t;
                const float* xp = x + (size_t)item * T_WIN;
                float x0 = xp[0], x1 = xp[1], x2 = xp[2], x3 = xp[3], x4 = xp[4];
                xs2T[item] = bss + x0 * ws0 + x1 * ws1 + x2 * ws2 + x3 * ws3 + x4 * ws4;
                xd2T[item] = bsd + x0 * wd0 + x1 * wd1 + x2 * wd2 + x3 * wd3 + x4 * wd4;
            }
        }
        return;
    }

    // ---- gram path: raw Gram tile, symmetric write (dot exactly symmetric)
    int g = blockIdx.x;                          // 0..527
    int a = (int)((sqrtf(8.f * g + 1.f) - 1.f) * 0.5f);
    while ((a + 1) * (a + 2) / 2 <= g) a++;
    while (a * (a + 1) / 2 > g) a--;
    int bq = g - a * (a + 1) / 2;                // 0..a
    int i0 = a * 64, j0 = bq * 64;

    {
        int r = t >> 2, c0 = t & 3;
        const float4* srcA = (const float4*)(emb + (size_t)(i0 + r) * D_EMB);
        const float4* srcB = (const float4*)(emb + (size_t)(j0 + r) * D_EMB);
#pragma unroll
        for (int k = 0; k < 4; k++) {
            int f4 = c0 + 4 * k;
            float4 v = srcA[f4];
            int d = 4 * f4;
            As[d][r] = v.x; As[d + 1][r] = v.y; As[d + 2][r] = v.z; As[d + 3][r] = v.w;
            float4 w = srcB[f4];
            Bs[d][r] = w.x; Bs[d + 1][r] = w.y; Bs[d + 2][r] = w.z; Bs[d + 3][r] = w.w;
        }
    }
    __syncthreads();

    int ti = t & 15, tj = t >> 4;
    float acc[4][4] = {};
#pragma unroll
    for (int d = 0; d < 64; d++) {
        float4 av = *(const float4*)&As[d][4 * ti];
        float4 bv = *(const float4*)&Bs[d][4 * tj];
        acc[0][0] += av.x * bv.x; acc[0][1] += av.x * bv.y; acc[0][2] += av.x * bv.z; acc[0][3] += av.x * bv.w;
        acc[1][0] += av.y * bv.x; acc[1][1] += av.y * bv.y; acc[1][2] += av.y * bv.z; acc[1][3] += av.y * bv.w;
        acc[2][0] += av.z * bv.x; acc[2][1] += av.z * bv.y; acc[2][2] += av.z * bv.z; acc[2][3] += av.z * bv.w;
        acc[3][0] += av.w * bv.x; acc[3][1] += av.w * bv.y; acc[3][2] += av.w * bv.z; acc[3][3] += av.w * bv.w;
    }

#pragma unroll
    for (int r = 0; r < 4; r++) {
        float4 o;
        o.x = acc[r][0]; o.y = acc[r][1]; o.z = acc[r][2]; o.w = acc[r][3];
        int i = i0 + 4 * ti + r;
        *(float4*)(dotM + (size_t)i * N_NODES + j0 + 4 * tj) = o;
        dotM[(size_t)(j0 + 4 * tj + 0) * N_NODES + i] = o.x;
        dotM[(size_t)(j0 + 4 * tj + 1) * N_NODES + i] = o.y;
        dotM[(size_t)(j0 + 4 * tj + 2) * N_NODES + i] = o.z;
        dotM[(size_t)(j0 + 4 * tj + 3) * N_NODES + i] = o.w;
    }
}

// ---------------- K2: top-21 selection — wave-pair split, on-the-fly norm ---
// [R5/R7 form; R9: 2-way split is the sweet spot (flush count dominates).]
__global__ __launch_bounds__(256) void k_select(
    const float* __restrict__ dotM, const float* __restrict__ norms,
    int* __restrict__ idxT) {
    __shared__ u64 candbuf[4][128];
    __shared__ u64 mbuf[2][64];
    int tid = threadIdx.x;
    int wid = tid >> 6, lane = tid & 63;
    int pair = wid >> 1;                 // row within block (0..1)
    int half = wid & 1;                  // 0: j<1024, 1: j>=1024
    int i = blockIdx.x * 2 + pair;
    int jbase = half * (N_NODES / 2);
    const float* row = dotM + (size_t)i * N_NODES + jbase;
    u64* buf = candbuf[wid];
    float ni = norms[i];

    u64 a = 0;
    u64 t = 0;
    int cnt = 0;
    float vcur = row[lane];
    float ncur = norms[jbase + lane];

#pragma unroll 1
    for (int c = 0; c < N_NODES / 128; c++) {   // 16 chunks of 64
        int j = c * 64 + lane;
        float dv = vcur, nv = ncur;
        if (c < N_NODES / 128 - 1) {
            vcur = row[j + 64];
            ncur = norms[jbase + j + 64];
        }
        float v = dv / (ni * nv);
        unsigned u = __float_as_uint(v);
        u = (u & 0x80000000u) ? ~u : (u | 0x80000000u);
        u64 key = ((u64)u << 32) | (unsigned)(~(j + jbase));
        unsigned long long ball = __ballot(key > t);
        if (ball) {
            int ofs = __popcll(ball & ((1ull << lane) - 1ull));
            if (key > t) buf[cnt + ofs] = key;
            cnt += (int)__popcll(ball);
            if (cnt >= 64) {
                u64 nk = buf[lane];
                nk = bitonic_sort64_desc(nk, lane);
                a = bitonic_merge_top64(a, nk, lane);
                t = __shfl(a, 20, 64);
                int rem = cnt - 64;
                u64 mv = (lane < rem) ? buf[64 + lane] : 0;
                if (lane < rem) buf[lane] = mv;
                cnt = rem;
            }
        }
    }
    while (cnt > 0) {
        int take = cnt < 64 ? cnt : 64;
        u64 nk = (lane < take) ? buf[lane] : 0;
        nk = bitonic_sort64_desc(nk, lane);
        a = bitonic_merge_top64(a, nk, lane);
        t = __shfl(a, 20, 64);
        int rem = cnt - take;
        u64 mv = (lane < rem) ? buf[take + lane] : 0;
        if (lane < rem) buf[lane] = mv;
        cnt = rem;
    }

    // pair merge: upper wave publishes its sorted top-64; lower wave merges
    if (half) mbuf[pair][lane] = a;
    __syncthreads();
    if (!half) {
        u64 bv = mbuf[pair][lane];
        a = bitonic_merge_top64(a, bv, lane);
        if (lane < TOPK) idxT[lane * N_NODES + i] = (int)(~(unsigned)a);
    }
}

// ---------------- K3: k_alpha — softmax -> packed paT[b][k][i]={idx,a-f16} --
// [R14 verified: paT u32 = (jk<<16)|f16(alpha), one dword/neighbor in k_msg.]
__global__ __launch_bounds__(256) void k_alpha(
    const int* __restrict__ idxT, const float* __restrict__ xs2T,
    const float* __restrict__ xd2T, const float* __restrict__ es_embP,
    const float* __restrict__ ed_embP, u32* __restrict__ paT) {
    __shared__ float sed[N_NODES];   // 8 KB
    int g = blockIdx.x;
    int b = g & 31;
    int i0 = (g >> 5) * 256;
    int t = threadIdx.x;

    {
        const float4* sxd = (const float4*)(xd2T + (size_t)b * N_NODES);
        const float4* sde = (const float4*)(ed_embP);
        float4* dst = (float4*)sed;
#pragma unroll
        for (int q = 0; q < 2; q++) {
            int idx = t + 256 * q;
            float4 u = sxd[idx];
            float4 v = sde[idx];
            dst[idx] = make_float4(u.x + v.x, u.y + v.y, u.z + v.z, u.w + v.w);
        }
    }
    __syncthreads();

    int i = i0 + t;
    float es = xs2T[(size_t)b * N_NODES + i] + es_embP[i];
    int jk[TOPK];
    float ev[TOPK];
    float m = -3e38f;
#pragma unroll
    for (int k = 0; k < TOPK; k++) {
        jk[k] = idxT[k * N_NODES + i];
        float e = es + sed[jk[k]];
        e = e > 0.f ? e : NEG_SLOPE * e;
        ev[k] = e;
        m = fmaxf(m, e);
    }
    float s = 0.f;
#pragma unroll
    for (int k = 0; k < TOPK; k++) {
        ev[k] = __expf(ev[k] - m);
        s += ev[k];
    }
    float inv = 1.0f / s;
#pragma unroll
    for (int k = 0; k < TOPK; k++) {
        u16 ah = __half_as_ushort(__float2half_rn(ev[k] * inv));
        paT[((size_t)b * TOPK + k) * N_NODES + i] = ((u32)jk[k] << 16) | (u32)ah;
    }
}

// ---------------- K4: message passing — f16 h-tile, packed pa, hfma2 --------
// [R15: re-land of R11's gather, exonerated (R11/R12 fails = workspace
//  overlap, fixed R13/R14). hts[2048][8] f16 (32 KB): one ds_read_b128
//  covers 8 dims -> total LDS + VMEM issue in the kernel HALVES vs R14
//  (each item's 21 paT dwords + 21 LDS reads issued by 8 blocks, not 16);
//  __hfma2 (v_pk_fma_f16) halves gather VALU. Block = (b, cc, half) = 512,
//  4/CU. f16 z-accum eps 1e-3, 8x finer than the bf16 obufT quantization
//  already dominating absmax (0.0625 vs 0.224 budget).]
__global__ __launch_bounds__(256, 4) void k_msg(
    const float* __restrict__ x, const float* __restrict__ W,
    const float* __restrict__ Wb, const u32* __restrict__ paT,
    const float* __restrict__ emb, uint4* __restrict__ obufT,
    float* __restrict__ stats, float* __restrict__ stats2) {
    __shared__ __align__(16) u32 hts[N_NODES][4];   // 32 KB, 8 f16/row
    __shared__ float sred[2][4][8];

    int g = blockIdx.x;                        // 512 = 32 b x 8 cc x 2 half
    int b = g & 31;
    int cc = (g >> 5) & 7;
    int half = g >> 8;
    int d0 = cc * 8;
    int ibase = half * (N_NODES / 2);
    int t = threadIdx.x;
    int wid = t >> 6, lane = t & 63;

    // ---- build f16 h-tile from x (full 2048 rows) ----
    float wc[8][T_WIN], wb8[8];
#pragma unroll
    for (int q = 0; q < 8; q++) {
        wb8[q] = Wb[d0 + q];
#pragma unroll
        for (int tt = 0; tt < T_WIN; tt++) wc[q][tt] = W[(d0 + q) * T_WIN + tt];
    }
    const float* xb = x + (size_t)b * N_NODES * T_WIN;
#pragma unroll
    for (int r = 0; r < 8; r++) {
        int row = t + 256 * r;
        const float* xr = xb + row * T_WIN;
        float x0 = xr[0], x1 = xr[1], x2 = xr[2], x3 = xr[3], x4 = xr[4];
        float h[8];
#pragma unroll
        for (int q = 0; q < 8; q++)
            h[q] = wb8[q] + x0 * wc[q][0] + x1 * wc[q][1] + x2 * wc[q][2]
                 + x3 * wc[q][3] + x4 * wc[q][4];
        __half2 p0 = __floats2half2_rn(h[0], h[1]);
        __half2 p1 = __floats2half2_rn(h[2], h[3]);
        __half2 p2 = __floats2half2_rn(h[4], h[5]);
        __half2 p3 = __floats2half2_rn(h[6], h[7]);
        uint4 sv;
        sv.x = *(u32*)&p0; sv.y = *(u32*)&p1; sv.z = *(u32*)&p2; sv.w = *(u32*)&p3;
        *(uint4*)&hts[row][0] = sv;
    }
    __syncthreads();

    // ---- gather: 1024 items (this half), 4 per thread ----
    float sacc[8] = {}, sacc2[8] = {};
    const u32* pb = paT + (size_t)b * TOPK * N_NODES;
#pragma unroll 1
    for (int r = 0; r < 4; r++) {
        int i = ibase + 256 * r + t;
        __half2 z01 = __floats2half2_rn(0.f, 0.f);
        __half2 z23 = z01, z45 = z01, z67 = z01;
#pragma unroll
        for (int k = 0; k < TOPK; k++) {
            u32 pa = pb[(size_t)k * N_NODES + i];    // coalesced, 1 dword
            int jk = (int)(pa >> 16);
            __half2 av = __half2half2(__ushort_as_half((u16)(pa & 0xFFFFu)));
            uint4 hv = *(const uint4*)&hts[jk][0];   // one ds_read_b128, 8 dims
            z01 = __hfma2(av, *(__half2*)&hv.x, z01);
            z23 = __hfma2(av, *(__half2*)&hv.y, z23);
            z45 = __hfma2(av, *(__half2*)&hv.z, z45);
            z67 = __hfma2(av, *(__half2*)&hv.w, z67);
        }
        float2 f01 = __half22float2(z01);
        float2 f23 = __half22float2(z23);
        float2 f45 = __half22float2(z45);
        float2 f67 = __half22float2(z67);
        float4 e0 = *(const float4*)(emb + (size_t)i * D_EMB + d0);
        float4 e1 = *(const float4*)(emb + (size_t)i * D_EMB + d0 + 4);
        float o[8];
        o[0] = fmaxf(f01.x, 0.f) * e0.x;
        o[1] = fmaxf(f01.y, 0.f) * e0.y;
        o[2] = fmaxf(f23.x, 0.f) * e0.z;
        o[3] = fmaxf(f23.y, 0.f) * e0.w;
        o[4] = fmaxf(f45.x, 0.f) * e1.x;
        o[5] = fmaxf(f45.y, 0.f) * e1.y;
        o[6] = fmaxf(f67.x, 0.f) * e1.z;
        o[7] = fmaxf(f67.y, 0.f) * e1.w;
        uint4 st;
        st.x = (u32)f2bf(o[0]) | ((u32)f2bf(o[1]) << 16);
        st.y = (u32)f2bf(o[2]) | ((u32)f2bf(o[3]) << 16);
        st.z = (u32)f2bf(o[4]) | ((u32)f2bf(o[5]) << 16);
        st.w = (u32)f2bf(o[6]) | ((u32)f2bf(o[7]) << 16);
        obufT[((size_t)cc * B_BATCH + b) * N_NODES + i] = st;
#pragma unroll
        for (int q = 0; q < 8; q++) {
            sacc[q] += o[q];
            sacc2[q] += o[q] * o[q];
        }
    }

    // ---- stats partials (both halves atomically add to the same slots) ----
#pragma unroll
    for (int q = 0; q < 8; q++) {
        sacc[q] = wave_sum(sacc[q]);
        sacc2[q] = wave_sum(sacc2[q]);
    }
    if (lane == 0) {
#pragma unroll
        for (int q = 0; q < 8; q++) {
            sred[0][wid][q] = sacc[q];
            sred[1][wid][q] = sacc2[q];
        }
    }
    __syncthreads();
    if (t < 16) {
        int q = t & 7, which = t >> 3;
        float v = sred[which][0][q] + sred[which][1][q] + sred[which][2][q] + sred[which][3][q];
        float* dst = which ? stats2 : stats;
        atomicAdd(&dst[(d0 + q) * STATS_STRIDE], v);
    }
}

// ---------------- K5: BN apply + relu + fc — bf16x8 c-panel sweep -----------
__global__ __launch_bounds__(256) void k_out(
    const uint4* __restrict__ obufT, const float* __restrict__ stats,
    const float* __restrict__ stats2, const float* __restrict__ gamma,
    const float* __restrict__ beta, const float* __restrict__ fc_w,
    const float* __restrict__ fc_b, float* __restrict__ out) {
    __shared__ float smean[64], sinv[64], sg[64], sb[64], sf[64];
    int t = threadIdx.x;
    int g = blockIdx.x;                 // 256 = 32 b x 8 n-chunks
    int b = g & 31, nc = g >> 5;
    int n = nc * 256 + t;
    const float invM = 1.0f / (float)BN_TOTAL;

    if (t < 64) {
        float mn = stats[t * STATS_STRIDE] * invM;
        float var = stats2[t * STATS_STRIDE] * invM - mn * mn;
        smean[t] = mn;
        sinv[t] = rsqrtf(var + EPS_BN);
        sg[t] = gamma[t]; sb[t] = beta[t]; sf[t] = fc_w[t];
    }
    __syncthreads();

    float fb = fc_b[0];
    float p = 0.f;
#pragma unroll
    for (int cc = 0; cc < 8; cc++) {
        uint4 hv = obufT[((size_t)cc * B_BATCH + b) * N_NODES + n];
        int d = cc * 8;
        float o[8];
        o[0] = bf2f((u16)(hv.x & 0xFFFFu)); o[1] = bf2f((u16)(hv.x >> 16));
        o[2] = bf2f((u16)(hv.y & 0xFFFFu)); o[3] = bf2f((u16)(hv.y >> 16));
        o[4] = bf2f((u16)(hv.z & 0xFFFFu)); o[5] = bf2f((u16)(hv.z >> 16));
        o[6] = bf2f((u16)(hv.w & 0xFFFFu)); o[7] = bf2f((u16)(hv.w >> 16));
#pragma unroll
        for (int q = 0; q < 8; q++) {
            float v = fmaxf((o[q] - smean[d + q]) * sinv[d + q] * sg[d + q] + sb[d + q], 0.f);
            p = fmaf(v, sf[d + q], p);
        }
    }
    out[b * N_NODES + n] = p + fb;
}

// ---------------- launch ----------------------------------------------------
extern "C" void kernel_launch(void* const* d_in, const int* in_sizes, int n_in,
                              void* d_out, int out_size, void* d_ws, size_t ws_size,
                              hipStream_t stream) {
    const float* x     = (const float*)d_in[0];
    const float* emb   = (const float*)d_in[1];
    const float* W     = (const float*)d_in[2];
    const float* Wb    = (const float*)d_in[3];
    const float* a_src = (const float*)d_in[4];
    const float* a_dst = (const float*)d_in[5];
    const float* gamma = (const float*)d_in[6];
    const float* beta  = (const float*)d_in[7];
    const float* fc_w  = (const float*)d_in[8];
    const float* fc_b  = (const float*)d_in[9];
    float* out = (float*)d_out;

    // Workspace map (re-derived from ELEMENT COUNTS):
    //   stats    [0,        4096)
    //   stats2   [4096,     8192)
    //   idxT     [8192,     180224)   21*2048*4      = 172,032
    //   norms    [180224,   188416)   2048*4         = 8,192
    //   es_embP  [188416,   196608)   2048*4         = 8,192
    //   ed_embP  [196608,   204800)   2048*4         = 8,192
    //   xs2T     [204800,   466944)   65536*4        = 262,144
    //   xd2T     [466944,   729088)   65536*4        = 262,144
    //   paT      [729088,   6234112)  32*21*2048*4   = 5,505,024
    //   dotM     [6234112,  23011328) 2048*2048*4    = 16,777,216
    //   obufT  = dotM alias (8.4 MB bf16x8; dotM dead after k_select)
    char* ws = (char*)d_ws;
    float* stats   = (float*)(ws + 0);
    float* stats2  = (float*)(ws + 4096);
    int*   idxT    = (int*)  (ws + 8192);
    float* norms   = (float*)(ws + 180224);
    float* es_embP = (float*)(ws + 188416);
    float* ed_embP = (float*)(ws + 196608);
    float* xs2T    = (float*)(ws + 204800);
    float* xd2T    = (float*)(ws + 466944);
    u32*   paT     = (u32*)  (ws + 729088);
    float* dotM    = (float*)(ws + 6234112);
    uint4* obufT   = (uint4*)dotM;
    // total: 23,011,328 bytes

    k_preg<<<1104, 256, 0, stream>>>(x, W, Wb, a_src, a_dst, emb,
                                     xs2T, xd2T, es_embP, ed_embP, norms,
                                     dotM, stats, stats2);
    k_select<<<N_NODES / 2, 256, 0, stream>>>(dotM, norms, idxT);
    k_alpha<<<256, 256, 0, stream>>>(idxT, xs2T, xd2T, es_embP, ed_embP, paT);
    k_msg<<<512, 256, 0, stream>>>(x, W, Wb, paT, emb, obufT, stats, stats2);
    k_out<<<256, 256, 0, stream>>>(obufT, stats, stats2, gamma, beta, fc_w, fc_b, out);
}